// Round 4
// baseline (236.290 us; speedup 1.0000x reference)
//
#include <hip/hip_runtime.h>

#define B_ 32
#define N_ 4096
#define C_ 16
#define D_ 256
#define NSPLIT 64
#define ROWS 64      // rows per block (N / NSPLIT)
#define RPS  32      // rows per substream (wave-pair)
#define NG   8       // groups of 4 rows per substream

// Wave = (row-substream, d-half): each lane holds float2 of v -> acc is only
// 32 VGPRs, total ~58 VGPRs -> 8 waves/SIMD, 8 blocks/CU = one fully
// co-resident round of the 2048-block grid. One 64-lane r-load covers
// 4 rows x 16 cats -> one ballot per group; accumulation is wave-uniform
// mask-FMA (m in {0,1} from SGPR), zero divergence. Next group (1 r + 4 v
// loads) prefetched while current group computes.
__global__ __launch_bounds__(256, 8)
void tensor_fusion_kernel(const float* __restrict__ r,
                          const float* __restrict__ v,
                          float* __restrict__ out) {
    const int b     = blockIdx.x >> 6;           // / NSPLIT
    const int chunk = blockIdx.x & (NSPLIT - 1);
    const int tid   = threadIdx.x;
    const int wave  = tid >> 6;
    const int lane  = tid & 63;
    const int sub   = wave >> 1;                 // row substream 0/1
    const int half  = wave & 1;                  // d-half 0/1
    const int d2    = half * 128 + (lane << 1);  // this lane's d (2 elems)

    const float* __restrict__ rb = r + (size_t)b * N_ * C_;
    const float* __restrict__ vp = v + (size_t)b * N_ * D_;
    const float scale = 1.0f / (float)N_;
    float* __restrict__ ob = out + (size_t)b * 17 * D_;

    float2 acc[16];
#pragma unroll
    for (int c = 0; c < 16; ++c) acc[c] = make_float2(0.f, 0.f);

    const int base = chunk * ROWS + sub * RPS;   // 32 consecutive rows
    const float* __restrict__ rptr = rb + (size_t)base * C_ + lane;
    const float* __restrict__ vptr = vp + (size_t)base * D_ + d2;

    float  rv, rv_n;
    float2 v0, v1, v2, v3, n0, n1, n2, n3;

#define LOADG(off, RV, A, Bq, Cq, Dq)                          \
    {                                                          \
        RV = rptr[(size_t)(off) * C_];                         \
        const float* _vn = vptr + (size_t)(off) * D_;          \
        A  = *(const float2*)(_vn + 0 * D_);                   \
        Bq = *(const float2*)(_vn + 1 * D_);                   \
        Cq = *(const float2*)(_vn + 2 * D_);                   \
        Dq = *(const float2*)(_vn + 3 * D_);                   \
    }

#define ACCROW(VV, MASK)                                       \
    {                                                          \
        const unsigned _m = (MASK);                            \
        _Pragma("unroll")                                      \
        for (int c = 0; c < 16; ++c) {                         \
            const float m = (_m & (1u << c)) ? 1.0f : 0.0f;    \
            acc[c].x += (VV).x * m;                            \
            acc[c].y += (VV).y * m;                            \
        }                                                      \
        if (_m == 0u) { /* all-below row: prob 0.5^16 */       \
            atomicAdd(&ob[16 * D_ + d2 + 0], (VV).x * scale);  \
            atomicAdd(&ob[16 * D_ + d2 + 1], (VV).y * scale);  \
        }                                                      \
    }

    LOADG(0, rv, v0, v1, v2, v3);

#pragma unroll
    for (int g = 0; g < NG; ++g) {
        if (g + 1 < NG) LOADG((g + 1) * 4, rv_n, n0, n1, n2, n3);

        const unsigned long long bal = __ballot(rv >= 0.5f);
        ACCROW(v0, (unsigned)(bal       ) & 0xFFFFu);
        ACCROW(v1, (unsigned)(bal >> 16 ) & 0xFFFFu);
        ACCROW(v2, (unsigned)(bal >> 32 ) & 0xFFFFu);
        ACCROW(v3, (unsigned)(bal >> 48 ) & 0xFFFFu);

        if (g + 1 < NG) { rv = rv_n; v0 = n0; v1 = n1; v2 = n2; v3 = n3; }
    }

    // ---- cross-substream reduction in LDS (sub0 stores, sub1 adds);
    // the two d-halves touch disjoint regions -> no race within a step
    __shared__ float2 lds2[16 * 128];   // 16 KiB
    const int li = half * 64 + lane;
    if (sub == 0) {
#pragma unroll
        for (int c = 0; c < 16; ++c) lds2[c * 128 + li] = acc[c];
    }
    __syncthreads();
    if (sub == 1) {
#pragma unroll
        for (int c = 0; c < 16; ++c) {
            float2 t = lds2[c * 128 + li];
            t.x += acc[c].x; t.y += acc[c].y;
            lds2[c * 128 + li] = t;
        }
    }
    __syncthreads();

    // ---- one coalesced atomicAdd stream per block (64 contributors/address)
    const float* lf = (const float*)lds2;
#pragma unroll
    for (int c = 0; c < 16; ++c) {
        atomicAdd(&ob[c * D_ + tid], lf[c * 256 + tid] * scale);
    }
}

extern "C" void kernel_launch(void* const* d_in, const int* in_sizes, int n_in,
                              void* d_out, int out_size, void* d_ws, size_t ws_size,
                              hipStream_t stream) {
    const float* r = (const float*)d_in[0];   // (B,N,C) fp32
    const float* v = (const float*)d_in[1];   // (B,N,D) fp32
    float* out = (float*)d_out;               // (B,C+1,D) fp32

    // harness re-poisons d_out to 0xAA before every timed launch
    hipMemsetAsync(out, 0, (size_t)out_size * sizeof(float), stream);

    dim3 grid(B_ * NSPLIT);
    tensor_fusion_kernel<<<grid, 256, 0, stream>>>(r, v, out);
}

// Round 5
// 208.336 us; speedup vs baseline: 1.1342x; 1.1342x over previous
//
#include <hip/hip_runtime.h>

#define B_ 32
#define N_ 4096
#define C_ 16
#define D_ 256
#define NSPLIT 64
#define ROWS (N_ / NSPLIT)   // 64 rows per block
#define RPW  (ROWS / 4)      // 16 rows per wave
#define NG   (RPW / 4)       // 4 groups of 4 rows per wave

// ---------------- Stage 1: per-block partial sums -> ws (NO atomics) -------
// One wave = one full row of D (64 lanes x float4). Rows in groups of 4:
// a single 64-lane r-load covers 4 rows x 16 cats -> one ballot per group.
// Accumulation: acc[c] += v * m, m in {0,1} from the wave-uniform ballot
// (scalar s_cselect, zero divergence). "All-below" rows (prob 0.5^16) go to
// a 17th register accumulator. Block partial (17 x 256) stored coalesced.
__global__ __launch_bounds__(256, 4)
void tf_stage1(const float* __restrict__ r,
               const float* __restrict__ v,
               float* __restrict__ ws) {
    const int b     = blockIdx.x >> 6;           // / NSPLIT
    const int chunk = blockIdx.x & (NSPLIT - 1);
    const int tid   = threadIdx.x;
    const int wave  = tid >> 6;
    const int lane  = tid & 63;
    const int d4    = lane << 2;

    const float* __restrict__ rb = r + (size_t)b * N_ * C_;
    const float* __restrict__ vp = v + (size_t)b * N_ * D_;

    float4 acc[17];                              // [16] = special (all-below)
#pragma unroll
    for (int c = 0; c < 17; ++c) acc[c] = make_float4(0.f, 0.f, 0.f, 0.f);

    const int base = chunk * ROWS + wave * RPW;  // 16 consecutive rows
    const float* __restrict__ rptr = rb + (size_t)base * C_ + lane;
    const float* __restrict__ vptr = vp + (size_t)base * D_ + d4;

    float  rv, rv_n;
    float4 v0, v1, v2, v3, n0, n1, n2, n3;

#define LOADG(off, RV, A, Bq, Cq, Dq)                          \
    {                                                          \
        RV = rptr[(size_t)(off) * C_];                         \
        const float* _vn = vptr + (size_t)(off) * D_;          \
        A  = *(const float4*)(_vn + 0 * D_);                   \
        Bq = *(const float4*)(_vn + 1 * D_);                   \
        Cq = *(const float4*)(_vn + 2 * D_);                   \
        Dq = *(const float4*)(_vn + 3 * D_);                   \
    }

#define ACCROW(VV, MASK)                                       \
    {                                                          \
        const unsigned _m = (MASK);                            \
        _Pragma("unroll")                                      \
        for (int c = 0; c < 16; ++c) {                         \
            const float m = (_m & (1u << c)) ? 1.0f : 0.0f;    \
            acc[c].x += (VV).x * m;                            \
            acc[c].y += (VV).y * m;                            \
            acc[c].z += (VV).z * m;                            \
            acc[c].w += (VV).w * m;                            \
        }                                                      \
        if (_m == 0u) { /* rare: prob 0.5^16 per row */        \
            acc[16].x += (VV).x; acc[16].y += (VV).y;          \
            acc[16].z += (VV).z; acc[16].w += (VV).w;          \
        }                                                      \
    }

    LOADG(0, rv, v0, v1, v2, v3);

#pragma unroll
    for (int g = 0; g < NG; ++g) {
        if (g + 1 < NG) LOADG((g + 1) * 4, rv_n, n0, n1, n2, n3);

        const unsigned long long bal = __ballot(rv >= 0.5f);
        ACCROW(v0, (unsigned)(bal       ) & 0xFFFFu);
        ACCROW(v1, (unsigned)(bal >> 16 ) & 0xFFFFu);
        ACCROW(v2, (unsigned)(bal >> 32 ) & 0xFFFFu);
        ACCROW(v3, (unsigned)(bal >> 48 ) & 0xFFFFu);

        if (g + 1 < NG) { rv = rv_n; v0 = n0; v1 = n1; v2 = n2; v3 = n3; }
    }

    // ---- cross-wave reduction in LDS (wave0 stores, waves 1..3 accumulate)
    __shared__ float4 lds4[17 * 64];    // 17 KiB
    if (wave == 0) {
#pragma unroll
        for (int c = 0; c < 17; ++c) lds4[c * 64 + lane] = acc[c];
    }
    __syncthreads();
    for (int w = 1; w < 4; ++w) {
        if (wave == w) {
#pragma unroll
            for (int c = 0; c < 17; ++c) {
                float4 t = lds4[c * 64 + lane];
                t.x += acc[c].x; t.y += acc[c].y;
                t.z += acc[c].z; t.w += acc[c].w;
                lds4[c * 64 + lane] = t;
            }
        }
        __syncthreads();
    }

    // ---- coalesced partial store: ws[(b*64+chunk)][17][256]
    float* __restrict__ wsb = ws + (size_t)blockIdx.x * 17 * D_;
    const float* lf = (const float*)lds4;
#pragma unroll
    for (int c = 0; c < 17; ++c) {
        wsb[c * D_ + tid] = lf[c * 256 + tid];
    }
}

// ---------------- Stage 2: reduce 64 chunk-partials per output element -----
// Block = (b, j) with j in [0,17); thread = d. Reads are 1 KB coalesced
// bursts strided by 17 KB; unroll-8 keeps 8 loads in flight per thread.
__global__ __launch_bounds__(256, 8)
void tf_stage2(const float* __restrict__ ws, float* __restrict__ out) {
    const int b = blockIdx.x / 17;
    const int j = blockIdx.x % 17;
    const int d = threadIdx.x;

    const float* __restrict__ p =
        ws + ((size_t)b * NSPLIT * 17 + j) * D_ + d;
    float s = 0.0f;
#pragma unroll 8
    for (int k = 0; k < NSPLIT; ++k) s += p[(size_t)k * 17 * D_];

    out[((size_t)b * 17 + j) * D_ + d] = s * (1.0f / (float)N_);
}

extern "C" void kernel_launch(void* const* d_in, const int* in_sizes, int n_in,
                              void* d_out, int out_size, void* d_ws, size_t ws_size,
                              hipStream_t stream) {
    const float* r = (const float*)d_in[0];   // (B,N,C) fp32
    const float* v = (const float*)d_in[1];   // (B,N,D) fp32
    float* out = (float*)d_out;               // (B,C+1,D) fp32
    float* ws  = (float*)d_ws;                // >= 34 MB used

    tf_stage1<<<dim3(B_ * NSPLIT), 256, 0, stream>>>(r, v, ws);
    tf_stage2<<<dim3(B_ * 17), 256, 0, stream>>>(ws, out);
    // stage2 writes every out element -> no memset of d_out needed
}